// Round 1
// baseline (102.467 us; speedup 1.0000x reference)
//
#include <hip/hip_runtime.h>
#include <math.h>

#define NUM_RBF 64
#define N_GRAPHS 64

// Gaussian RBF + cosine-cutoff edge energy, segment-summed per graph.
// Stage 1: grid-stride over edges, per-block LDS bins, partials -> d_ws.
// Stage 2: reduce partials -> d_out (overwrites every element, so poison-safe).

__global__ __launch_bounds__(256) void edge_energy_kernel(
    const float* __restrict__ pos,
    const float* __restrict__ rbf_params,
    const float* __restrict__ radial_filters,
    const int*  __restrict__ edge_index,
    const int*  __restrict__ atom_types,
    const int*  __restrict__ batch,
    float* __restrict__ partial,   // [gridDim.x * N_GRAPHS]
    int E, int T)
{
    __shared__ float bins[N_GRAPHS];
    for (int i = threadIdx.x; i < N_GRAPHS; i += blockDim.x) bins[i] = 0.0f;
    __syncthreads();

    const float CUTOFF      = 5.0f;
    const float gamma       = (NUM_RBF / CUTOFF) * (NUM_RBF / CUTOFF);   // 163.84
    const float spacing     = CUTOFF / (float)(NUM_RBF - 1);             // 5/63
    const float inv_spacing = (float)(NUM_RBF - 1) / CUTOFF;
    const float pi_over_c   = (float)M_PI / CUTOFF;

    const int stride = gridDim.x * blockDim.x;
    for (int e = blockIdx.x * blockDim.x + threadIdx.x; e < E; e += stride) {
        const int src = edge_index[e];
        const int dst = edge_index[E + e];

        const float dx = pos[3 * dst + 0] - pos[3 * src + 0];
        const float dy = pos[3 * dst + 1] - pos[3 * src + 1];
        const float dz = pos[3 * dst + 2] - pos[3 * src + 2];
        const float d  = sqrtf(dx * dx + dy * dy + dz * dz + 1e-12f);

        if (d < CUTOFF) {
            const int ts = atom_types[src];
            const int tr = atom_types[dst];
            const int lo = min(ts, tr);
            const int hi = max(ts, tr);
            const int base = (lo * T + hi) * NUM_RBF;

            // 16-wide window around the nearest center: tail terms < e^-58.
            int m0 = (int)(d * inv_spacing + 0.5f) - 8;
            m0 = max(0, min(NUM_RBF - 16, m0));

            float acc = 0.0f;
#pragma unroll
            for (int k = 0; k < 16; ++k) {
                const int m = m0 + k;
                const float delta = d - (float)m * spacing;
                const float g = __expf(-gamma * delta * delta);
                acc += g * radial_filters[base + m] * rbf_params[base + m];
            }
            const float fc = 0.5f * (__cosf(pi_over_c * d) + 1.0f);
            atomicAdd(&bins[batch[src]], acc * fc);
        }
    }

    __syncthreads();
    for (int i = threadIdx.x; i < N_GRAPHS; i += blockDim.x)
        partial[blockIdx.x * N_GRAPHS + i] = bins[i];
}

__global__ __launch_bounds__(256) void reduce_kernel(
    const float* __restrict__ partial,
    float* __restrict__ out,
    int nblocks)
{
    const int g = blockIdx.x;           // one block per graph bin
    float s = 0.0f;
    for (int i = threadIdx.x; i < nblocks; i += blockDim.x)
        s += partial[i * N_GRAPHS + g];

    // wave reduce (64-wide), then cross-wave via LDS
    for (int off = 32; off > 0; off >>= 1)
        s += __shfl_down(s, off, 64);

    __shared__ float red[4];            // 256 threads = 4 waves
    const int wave = threadIdx.x >> 6;
    const int lane = threadIdx.x & 63;
    if (lane == 0) red[wave] = s;
    __syncthreads();
    if (threadIdx.x == 0)
        out[g] = red[0] + red[1] + red[2] + red[3];
}

extern "C" void kernel_launch(void* const* d_in, const int* in_sizes, int n_in,
                              void* d_out, int out_size, void* d_ws, size_t ws_size,
                              hipStream_t stream) {
    const float* pos            = (const float*)d_in[0];
    const float* rbf_params     = (const float*)d_in[1];
    const float* radial_filters = (const float*)d_in[2];
    const int*   edge_index     = (const int*)d_in[3];
    const int*   atom_types     = (const int*)d_in[4];
    const int*   batch          = (const int*)d_in[5];
    float*       out            = (float*)d_out;

    const int E = in_sizes[3] / 2;
    // T*T*NUM_RBF == in_sizes[1]
    int T = 1;
    while ((T + 1) * (T + 1) * NUM_RBF <= in_sizes[1]) ++T;

    // partial bins live in workspace; cap by ws_size
    int nblocks = 2048;
    const size_t need = (size_t)nblocks * N_GRAPHS * sizeof(float);
    if (ws_size < need) {
        nblocks = (int)(ws_size / (N_GRAPHS * sizeof(float)));
        if (nblocks < 1) nblocks = 1;
    }
    float* partial = (float*)d_ws;

    edge_energy_kernel<<<nblocks, 256, 0, stream>>>(
        pos, rbf_params, radial_filters, edge_index, atom_types, batch,
        partial, E, T);

    reduce_kernel<<<N_GRAPHS, 256, 0, stream>>>(partial, out, nblocks);
}